// Round 1
// baseline (667.666 us; speedup 1.0000x reference)
//
#include <hip/hip_runtime.h>
#include <hip/hip_bf16.h>
#include <stdint.h>

#define BATCH 256
#define NP    196
#define PP    768
#define DD    768
#define FM    40
#define FU    156

// output element offsets (f32 elements, concatenated in return order)
#define O_UE 0ull          // unmasked_embeddings [256,156,768]
#define O_ME 30670848ull   // masked_embeddings   [256,40,768]
#define O_UP 38535168ull   // unmasked_positions  [256,156,768]
#define O_MI 69206016ull   // mask_indices        [256,40]   (as float)
#define O_UI 69216256ull   // unmask_indices      [256,156]  (as float)

typedef __attribute__((ext_vector_type(8))) short short8;
typedef __attribute__((ext_vector_type(4))) float f32x4;

__device__ __forceinline__ unsigned short bf16_rne(float x) {
    unsigned u = __float_as_uint(x);
    u += 0x7FFFu + ((u >> 16) & 1u);
    return (unsigned short)(u >> 16);
}
__device__ __forceinline__ float bf16_f(unsigned short h) {
    return __uint_as_float(((unsigned)h) << 16);
}

// ---------------------------------------------------------------------------
// Kernel 1: transpose W -> [kt][d][perm-k 32] hi/lo bf16 planes in workspace.
// perm chunk g holds k = {4g..4g+3, 16+4g..16+4g+3} so a GEMM lane's 8
// operand bf16 are one contiguous 16B ds_read_b128.
// ---------------------------------------------------------------------------
__global__ __launch_bounds__(256) void prep_w_kernel(
    const float* __restrict__ W,
    unsigned short* __restrict__ wt_hi,
    unsigned short* __restrict__ wt_lo) {
    const int d  = blockIdx.x * 256 + threadIdx.x;  // 0..767
    const int kt = blockIdx.y;                      // 0..23
    alignas(16) unsigned short hi[32];
    alignas(16) unsigned short lo[32];
#pragma unroll
    for (int g = 0; g < 4; ++g) {
#pragma unroll
        for (int j = 0; j < 8; ++j) {
            int k = (j < 4) ? (4 * g + j) : (16 + 4 * g + (j - 4));
            float x = W[(size_t)(kt * 32 + k) * DD + d];
            unsigned short h = bf16_rne(x);
            hi[g * 8 + j] = h;
            lo[g * 8 + j] = bf16_rne(x - bf16_f(h));
        }
    }
    size_t base = ((size_t)kt * DD + d) * 32;
    uint4* dh = (uint4*)(wt_hi + base);
    uint4* dl = (uint4*)(wt_lo + base);
    const uint4* sh = (const uint4*)hi;
    const uint4* sl = (const uint4*)lo;
#pragma unroll
    for (int i = 0; i < 4; ++i) { dh[i] = sh[i]; dl[i] = sl[i]; }
}

// ---------------------------------------------------------------------------
// Kernel 2: mtok_emb = mask_token @ W + b   (f32, exact-ish)
// ---------------------------------------------------------------------------
__global__ __launch_bounds__(256) void mtok_kernel(
    const float* __restrict__ mask_token,
    const float* __restrict__ W,
    const float* __restrict__ bias,
    float* __restrict__ mtok_out) {
    int d = blockIdx.x * 256 + threadIdx.x;
    if (d >= DD) return;
    float acc = 0.f;
    for (int p = 0; p < PP; ++p) acc += mask_token[p] * W[(size_t)p * DD + d];
    mtok_out[d] = acc + bias[d];
}

// ---------------------------------------------------------------------------
// Kernel 3: per-image selection. Bitonic sort of packed keys reproduces
// jax.lax.top_k (descending, stable ties -> lower index). Complement via
// block prefix-scan.
// ---------------------------------------------------------------------------
__global__ __launch_bounds__(256) void select_kernel(
    const float* __restrict__ patches,
    const float* __restrict__ rand_u,
    float* __restrict__ out,
    int* __restrict__ gidx,
    int* __restrict__ pidx,
    int* __restrict__ midx,
    int* __restrict__ valid_arr) {

    const int b = blockIdx.x;
    const int tid = threadIdx.x;
    __shared__ unsigned long long key[256];
    __shared__ int s_flag[256];
    __shared__ int s_scan[256];
    __shared__ int wsum[4];

    // valid = any(x != 0)  (== mean(|x|) > 0)
    int v = 0;
    if (tid < NP) {
        const float* row = patches + ((size_t)b * NP + tid) * PP;
        for (int p = 0; p < PP; ++p) {
            if (row[p] != 0.0f) { v = 1; break; }
        }
    }
    unsigned long long bal = __ballot(v != 0);
    if ((tid & 63) == 0) wsum[tid >> 6] = __popcll(bal);
    __syncthreads();
    int count = wsum[0] + wsum[1] + wsum[2] + wsum[3];
    bool valid_image = (count >= 20) && (ceilf((float)count * 0.4f) >= 40.0f);

    unsigned long long k = 0ull;
    if (tid < NP) {
        float u = rand_u[(size_t)b * NP + tid];
        float score = v ? (1000.0f + 1000.0f * u) : (10.0f * u);
        k = (((unsigned long long)__float_as_uint(score)) << 32) |
            (unsigned long long)(unsigned)(~tid);
    }
    key[tid] = k;
    __syncthreads();

    // bitonic sort, 256 elems, descending
    for (int kk = 2; kk <= 256; kk <<= 1) {
        for (int j = kk >> 1; j > 0; j >>= 1) {
            int ixj = tid ^ j;
            if (ixj > tid) {
                unsigned long long a = key[tid], c = key[ixj];
                bool desc = ((tid & kk) == 0);
                if (desc ? (a < c) : (a > c)) { key[tid] = c; key[ixj] = a; }
            }
            __syncthreads();
        }
    }

    int m_out = 0;
    if (tid < FM) {
        int idx = (int)(~(unsigned)(key[tid] & 0xFFFFFFFFull));
        m_out = valid_image ? idx : 0;
        midx[b * FM + tid] = m_out;
        out[O_MI + (size_t)b * FM + tid] = (float)m_out;
    }
    s_flag[tid] = 0;
    __syncthreads();
    if (tid < FM) s_flag[m_out] = 1;
    __syncthreads();

    int x = (tid < NP) ? (1 - s_flag[tid]) : 0;
    s_scan[tid] = x;
    __syncthreads();
    for (int off = 1; off < 256; off <<= 1) {
        int t2 = (tid >= off) ? s_scan[tid - off] : 0;
        __syncthreads();
        s_scan[tid] += t2;
        __syncthreads();
    }
    int pos = s_scan[tid] - x;  // exclusive scan of unmasked flags

    if (valid_image) {
        if (tid < NP && !s_flag[tid] && pos < FU) {
            gidx[(size_t)b * FU + pos] = b * NP + tid;
            pidx[(size_t)b * FU + pos] = tid;
            out[O_UI + (size_t)b * FU + pos] = (float)tid;
        }
    } else {
        if (tid < FU) {
            gidx[(size_t)b * FU + tid] = b * NP + tid;
            pidx[(size_t)b * FU + tid] = tid;
            out[O_UI + (size_t)b * FU + tid] = (float)tid;
        }
    }
    if (tid == 0) valid_arr[b] = valid_image ? 1 : 0;
}

// ---------------------------------------------------------------------------
// Kernel 4: gathered GEMM, split-bf16 x3 MFMA.
//   MFMA-A = W^T tile (from LDS, M-dim = d cols), MFMA-B = patches rows
//   (per-lane global f32 -> hi/lo in registers). Block tile 128 rows x 128 d,
//   4 waves (2 d x 2 row), wave tile 64x64, BK=32.
//   Epilogue: +bias +pos, writes unmasked_embeddings AND unmasked_positions.
// ---------------------------------------------------------------------------
__global__ __launch_bounds__(256) void gemm_kernel(
    const float* __restrict__ patches,
    const unsigned short* __restrict__ wt_hi,
    const unsigned short* __restrict__ wt_lo,
    const float* __restrict__ bias,
    const float* __restrict__ pos_table,
    const int* __restrict__ gidx,
    const int* __restrict__ pidx,
    float* __restrict__ out) {

    __shared__ __align__(16) unsigned short lds_hi[128 * 32];
    __shared__ __align__(16) unsigned short lds_lo[128 * 32];

    const int tid = threadIdx.x;
    const int l   = tid & 63;
    const int w   = tid >> 6;
    const int wd  = w >> 1;   // d-dim wave (0..1)
    const int wp  = w & 1;    // row-dim wave (0..1)
    const int ct  = blockIdx.x;  // 0..5   (d tiles)
    const int rt  = blockIdx.y;  // 0..311 (row tiles)
    const int l15 = l & 15;
    const int g   = l >> 4;      // 0..3

    // per-lane gathered rows (MFMA N-dim)
    int rflat[4];
    const float* prow[4];
    int ppos[4];
#pragma unroll
    for (int ci = 0; ci < 4; ++ci) {
        int r = rt * 128 + wp * 64 + ci * 16 + l15;
        rflat[ci] = r;
        prow[ci] = patches + (size_t)gidx[r] * PP;
        ppos[ci] = pidx[r];
    }

    f32x4 acc[4][4];
    const f32x4 z = {0.f, 0.f, 0.f, 0.f};
#pragma unroll
    for (int mi = 0; mi < 4; ++mi)
#pragma unroll
        for (int ci = 0; ci < 4; ++ci) acc[mi][ci] = z;

    const size_t tile_us0 = (size_t)(ct * 128) * 32;
    uint4* ldsv_hi = (uint4*)lds_hi;
    uint4* ldsv_lo = (uint4*)lds_lo;

    for (int kt = 0; kt < 24; ++kt) {
        // patches B-fragments: per-lane global f32, split to hi/lo bf16
        short8 phi[4], plo[4];
#pragma unroll
        for (int ci = 0; ci < 4; ++ci) {
            const float* p = prow[ci] + kt * 32 + 4 * g;
            const float4 a  = *(const float4*)p;
            const float4 b2 = *(const float4*)(p + 16);
            float vs[8] = {a.x, a.y, a.z, a.w, b2.x, b2.y, b2.z, b2.w};
            short8 h8, l8;
#pragma unroll
            for (int e = 0; e < 8; ++e) {
                unsigned short h = bf16_rne(vs[e]);
                h8[e] = (short)h;
                l8[e] = (short)bf16_rne(vs[e] - bf16_f(h));
            }
            phi[ci] = h8;
            plo[ci] = l8;
        }

        // stage W tile (contiguous 8KB per plane, reg-staged)
        const uint4* sh = (const uint4*)(wt_hi + (size_t)kt * DD * 32 + tile_us0);
        const uint4* sl = (const uint4*)(wt_lo + (size_t)kt * DD * 32 + tile_us0);
        ldsv_hi[tid]       = sh[tid];
        ldsv_hi[tid + 256] = sh[tid + 256];
        ldsv_lo[tid]       = sl[tid];
        ldsv_lo[tid + 256] = sl[tid + 256];
        __syncthreads();

#pragma unroll
        for (int mi = 0; mi < 4; ++mi) {
            const int rowbase = (wd * 64 + mi * 16 + l15) * 32 + g * 8;
            short8 whi = *(const short8*)(lds_hi + rowbase);
            short8 wlo = *(const short8*)(lds_lo + rowbase);
#pragma unroll
            for (int ci = 0; ci < 4; ++ci) {
                acc[mi][ci] = __builtin_amdgcn_mfma_f32_16x16x32_bf16(
                    whi, phi[ci], acc[mi][ci], 0, 0, 0);
                acc[mi][ci] = __builtin_amdgcn_mfma_f32_16x16x32_bf16(
                    whi, plo[ci], acc[mi][ci], 0, 0, 0);
                acc[mi][ci] = __builtin_amdgcn_mfma_f32_16x16x32_bf16(
                    wlo, phi[ci], acc[mi][ci], 0, 0, 0);
            }
        }
        __syncthreads();
    }

    // epilogue: out = acc + bias + pos ; also emit gathered positions
#pragma unroll
    for (int mi = 0; mi < 4; ++mi) {
        const int dc = ct * 128 + wd * 64 + mi * 16 + 4 * g;
        const float4 b4 = *(const float4*)(bias + dc);
#pragma unroll
        for (int ci = 0; ci < 4; ++ci) {
            const float4 p4 = *(const float4*)(pos_table + (size_t)ppos[ci] * DD + dc);
            f32x4 o = acc[mi][ci];
            float4 r;
            r.x = o[0] + b4.x + p4.x;
            r.y = o[1] + b4.y + p4.y;
            r.z = o[2] + b4.z + p4.z;
            r.w = o[3] + b4.w + p4.w;
            size_t ro = (size_t)rflat[ci] * DD + dc;
            *(float4*)(out + O_UE + ro) = r;
            *(float4*)(out + O_UP + ro) = p4;
        }
    }
}

// ---------------------------------------------------------------------------
// Kernel 5: masked_embeddings = validity * (mtok_emb + pos[mask_idx])
// ---------------------------------------------------------------------------
__global__ __launch_bounds__(192) void masked_kernel(
    const float* __restrict__ pos_table,
    const float* __restrict__ mtok,
    const int* __restrict__ midx,
    const int* __restrict__ valid_arr,
    float* __restrict__ out) {
    const int j = blockIdx.x;   // 0..39
    const int b = blockIdx.y;   // 0..255
    const int d = threadIdx.x * 4;
    float4 r = {0.f, 0.f, 0.f, 0.f};
    if (valid_arr[b]) {
        int pi = midx[b * FM + j];
        const float4 m4 = *(const float4*)(mtok + d);
        const float4 p4 = *(const float4*)(pos_table + (size_t)pi * DD + d);
        r.x = m4.x + p4.x; r.y = m4.y + p4.y;
        r.z = m4.z + p4.z; r.w = m4.w + p4.w;
    }
    *(float4*)(out + O_ME + ((size_t)b * FM + j) * DD + d) = r;
}

// ---------------------------------------------------------------------------
extern "C" void kernel_launch(void* const* d_in, const int* in_sizes, int n_in,
                              void* d_out, int out_size, void* d_ws, size_t ws_size,
                              hipStream_t stream) {
    const float* patches   = (const float*)d_in[0];
    const float* rand_u    = (const float*)d_in[1];
    const float* W         = (const float*)d_in[2];
    const float* bias      = (const float*)d_in[3];
    const float* pos_table = (const float*)d_in[4];
    const float* mask_tok  = (const float*)d_in[5];
    float* out = (float*)d_out;

    char* ws = (char*)d_ws;
    int*            gidx   = (int*)(ws + 0);              // 39936 ints
    int*            pidx   = (int*)(ws + 159744);         // 39936 ints
    int*            midx   = (int*)(ws + 319488);         // 10240 ints
    int*            valid  = (int*)(ws + 360448);         // 256 ints
    float*          mtok   = (float*)(ws + 361472);       // 768 f32
    unsigned short* wt_hi  = (unsigned short*)(ws + 364544);   // 589824 bf16
    unsigned short* wt_lo  = (unsigned short*)(ws + 1544192);  // 589824 bf16

    prep_w_kernel<<<dim3(3, 24), dim3(256), 0, stream>>>(W, wt_hi, wt_lo);
    mtok_kernel<<<dim3(3), dim3(256), 0, stream>>>(mask_tok, W, bias, mtok);
    select_kernel<<<dim3(BATCH), dim3(256), 0, stream>>>(patches, rand_u, out,
                                                         gidx, pidx, midx, valid);
    gemm_kernel<<<dim3(6, 312), dim3(256), 0, stream>>>(patches, wt_hi, wt_lo,
                                                        bias, pos_table, gidx,
                                                        pidx, out);
    masked_kernel<<<dim3(FM, BATCH), dim3(192), 0, stream>>>(pos_table, mtok,
                                                             midx, valid, out);
}